// Round 2
// baseline (919.462 us; speedup 1.0000x reference)
//
#include <hip/hip_runtime.h>

#define NN 12288
#define EE 196608

typedef unsigned short u16;
typedef short short8 __attribute__((ext_vector_type(8)));
typedef float f32x4 __attribute__((ext_vector_type(4)));

__device__ __forceinline__ u16 f2bf(float f) {
    unsigned u = __float_as_uint(f);
    u += 0x7fffu + ((u >> 16) & 1u);   // round-to-nearest-even
    return (u16)(u >> 16);
}
__device__ __forceinline__ short8 cvt8(f32x4 a, f32x4 b) {
    short8 r;
    r[0] = (short)f2bf(a[0]); r[1] = (short)f2bf(a[1]);
    r[2] = (short)f2bf(a[2]); r[3] = (short)f2bf(a[3]);
    r[4] = (short)f2bf(b[0]); r[5] = (short)f2bf(b[1]);
    r[6] = (short)f2bf(b[2]); r[7] = (short)f2bf(b[3]);
    return r;
}

// ---------------- degree count: deg[col] += 1 over E edges ----------------
__global__ __launch_bounds__(256) void k_deg(const int* __restrict__ ei,
                                             int* __restrict__ deg) {
    int i = blockIdx.x * 256 + threadIdx.x;   // grid covers exactly EE
    atomicAdd(&deg[ei[EE + i]], 1);
}

// ------- single-block scan: offsets (exclusive), cursor copy, dinv --------
__global__ __launch_bounds__(1024) void k_scan(const int* __restrict__ deg,
                                               int* __restrict__ offs,
                                               int* __restrict__ cursor,
                                               float* __restrict__ dinv) {
    __shared__ int s[1024];
    int t = threadIdx.x;
    int base = t * 12;                        // 1024*12 = 12288
    int v[12];
    int sum = 0;
#pragma unroll
    for (int k = 0; k < 12; ++k) {
        v[k] = deg[base + k];
        sum += v[k];
        dinv[base + k] = rsqrtf((float)(v[k] + 1));  // +1 self-loop
    }
    s[t] = sum;
    __syncthreads();
    for (int off = 1; off < 1024; off <<= 1) {
        int val = (t >= off) ? s[t - off] : 0;
        __syncthreads();
        s[t] += val;
        __syncthreads();
    }
    int run = s[t] - sum;   // exclusive prefix for this thread's chunk
#pragma unroll
    for (int k = 0; k < 12; ++k) {
        offs[base + k] = run;
        cursor[base + k] = run;
        run += v[k];
    }
    if (t == 1023) offs[NN] = run;   // == EE
}

// ---------------- CSR fill via counting sort ----------------
__global__ __launch_bounds__(256) void k_csr(const int* __restrict__ ei,
                                             int* __restrict__ cursor,
                                             int* __restrict__ csr) {
    int i = blockIdx.x * 256 + threadIdx.x;
    int r = ei[i];
    int c = ei[EE + i];
    int p = atomicAdd(&cursor[c], 1);
    csr[p] = r;
}

// ------- small dense: Rt[o][n] = relu(x@Wh^T) (bf16), XW[n][o] = x@Wc^T (f32)
__global__ __launch_bounds__(256) void k_xw(const float* __restrict__ X,
                                            const float* __restrict__ Wh,
                                            const float* __restrict__ Wc,
                                            u16* __restrict__ Rt,
                                            float* __restrict__ XW) {
    const int o = blockIdx.x & 63;
    const int node = (blockIdx.x >> 6) * 256 + threadIdx.x;
    const f32x4* xp  = (const f32x4*)(X + (size_t)node * 64);
    const f32x4* whp = (const f32x4*)(Wh + (size_t)o * 64);
    const f32x4* wcp = (const f32x4*)(Wc + (size_t)o * 64);
    float ah = 0.f, ac = 0.f;
#pragma unroll
    for (int g = 0; g < 16; ++g) {
        f32x4 xv = xp[g];
        f32x4 hv = whp[g];
        f32x4 cv = wcp[g];
#pragma unroll
        for (int j = 0; j < 4; ++j) {
            ah += xv[j] * hv[j];
            ac += xv[j] * cv[j];
        }
    }
    Rt[(size_t)o * NN + node] = f2bf(ah > 0.f ? ah : 0.f);
    XW[(size_t)node * 64 + o] = ac;
}

// ---------------- streaming MFMA GEMM: HhP[split] = Lsym_chunk @ R ----------
// grid = 96 row-tiles * sp splits, 256 thr (4 waves x 32 rows). No LDS:
// A (fp32, 604 MB, read-once) streamed nontemporal + cvt to bf16 in-reg;
// B (Rt bf16, 1.5 MB, L2-resident) read direct.
__global__ __launch_bounds__(256, 3) void k_gemm(const float* __restrict__ Ls,
                                                 const u16* __restrict__ Rt,
                                                 float* __restrict__ HhP,
                                                 int spshift, int kchunk) {
    const int bi = blockIdx.x;
    const int split = bi & ((1 << spshift) - 1);
    const int tile = bi >> spshift;
    const int tid = threadIdx.x;
    const int lane = tid & 63;
    const int w = tid >> 6;
    const int m = lane & 15;
    const int q = lane >> 4;
    const int kbeg = split * kchunk;
    const int row0 = tile * 128 + w * 32;
    const int steps = kchunk >> 5;

    const float* A0 = Ls + (size_t)(row0 + m) * NN + kbeg + q * 8;
    const float* A1 = A0 + (size_t)16 * NN;
    const u16* Bp = Rt + (size_t)m * NN + kbeg + q * 8;

    f32x4 acc[2][4];
#pragma unroll
    for (int g = 0; g < 2; ++g)
#pragma unroll
        for (int t = 0; t < 4; ++t) acc[g][t] = (f32x4){0.f, 0.f, 0.f, 0.f};

    f32x4 a0lo = __builtin_nontemporal_load((const f32x4*)A0);
    f32x4 a0hi = __builtin_nontemporal_load((const f32x4*)(A0 + 4));
    f32x4 a1lo = __builtin_nontemporal_load((const f32x4*)A1);
    f32x4 a1hi = __builtin_nontemporal_load((const f32x4*)(A1 + 4));
    short8 b0 = *(const short8*)(Bp);
    short8 b1 = *(const short8*)(Bp + (size_t)16 * NN);
    short8 b2 = *(const short8*)(Bp + (size_t)32 * NN);
    short8 b3 = *(const short8*)(Bp + (size_t)48 * NN);

    for (int it = 0; it < steps - 1; ++it) {
        A0 += 32; A1 += 32; Bp += 32;
        f32x4 na0lo = __builtin_nontemporal_load((const f32x4*)A0);
        f32x4 na0hi = __builtin_nontemporal_load((const f32x4*)(A0 + 4));
        f32x4 na1lo = __builtin_nontemporal_load((const f32x4*)A1);
        f32x4 na1hi = __builtin_nontemporal_load((const f32x4*)(A1 + 4));
        short8 nb0 = *(const short8*)(Bp);
        short8 nb1 = *(const short8*)(Bp + (size_t)16 * NN);
        short8 nb2 = *(const short8*)(Bp + (size_t)32 * NN);
        short8 nb3 = *(const short8*)(Bp + (size_t)48 * NN);
        short8 a0 = cvt8(a0lo, a0hi);
        short8 a1 = cvt8(a1lo, a1hi);
        acc[0][0] = __builtin_amdgcn_mfma_f32_16x16x32_bf16(a0, b0, acc[0][0], 0, 0, 0);
        acc[1][0] = __builtin_amdgcn_mfma_f32_16x16x32_bf16(a1, b0, acc[1][0], 0, 0, 0);
        acc[0][1] = __builtin_amdgcn_mfma_f32_16x16x32_bf16(a0, b1, acc[0][1], 0, 0, 0);
        acc[1][1] = __builtin_amdgcn_mfma_f32_16x16x32_bf16(a1, b1, acc[1][1], 0, 0, 0);
        acc[0][2] = __builtin_amdgcn_mfma_f32_16x16x32_bf16(a0, b2, acc[0][2], 0, 0, 0);
        acc[1][2] = __builtin_amdgcn_mfma_f32_16x16x32_bf16(a1, b2, acc[1][2], 0, 0, 0);
        acc[0][3] = __builtin_amdgcn_mfma_f32_16x16x32_bf16(a0, b3, acc[0][3], 0, 0, 0);
        acc[1][3] = __builtin_amdgcn_mfma_f32_16x16x32_bf16(a1, b3, acc[1][3], 0, 0, 0);
        a0lo = na0lo; a0hi = na0hi; a1lo = na1lo; a1hi = na1hi;
        b0 = nb0; b1 = nb1; b2 = nb2; b3 = nb3;
    }
    {
        short8 a0 = cvt8(a0lo, a0hi);
        short8 a1 = cvt8(a1lo, a1hi);
        acc[0][0] = __builtin_amdgcn_mfma_f32_16x16x32_bf16(a0, b0, acc[0][0], 0, 0, 0);
        acc[1][0] = __builtin_amdgcn_mfma_f32_16x16x32_bf16(a1, b0, acc[1][0], 0, 0, 0);
        acc[0][1] = __builtin_amdgcn_mfma_f32_16x16x32_bf16(a0, b1, acc[0][1], 0, 0, 0);
        acc[1][1] = __builtin_amdgcn_mfma_f32_16x16x32_bf16(a1, b1, acc[1][1], 0, 0, 0);
        acc[0][2] = __builtin_amdgcn_mfma_f32_16x16x32_bf16(a0, b2, acc[0][2], 0, 0, 0);
        acc[1][2] = __builtin_amdgcn_mfma_f32_16x16x32_bf16(a1, b2, acc[1][2], 0, 0, 0);
        acc[0][3] = __builtin_amdgcn_mfma_f32_16x16x32_bf16(a0, b3, acc[0][3], 0, 0, 0);
        acc[1][3] = __builtin_amdgcn_mfma_f32_16x16x32_bf16(a1, b3, acc[1][3], 0, 0, 0);
    }

    // C/D layout: col = lane&15 (=m), row = q*4 + r  (within each 16x16 tile)
    float* P = HhP + (size_t)split * (NN * 64) + (size_t)row0 * 64;
#pragma unroll
    for (int g = 0; g < 2; ++g)
#pragma unroll
        for (int t = 0; t < 4; ++t)
#pragma unroll
            for (int r = 0; r < 4; ++r)
                P[(size_t)(g * 16 + q * 4 + r) * 64 + t * 16 + m] = acc[g][t][r];
}

// ------- final: out = aL*(gather(XW,csr,dinv)+self+b) + aH*sum(HhP) ---------
__global__ __launch_bounds__(256) void k_final(const float* __restrict__ XW,
                                               const float* __restrict__ dinv,
                                               const int* __restrict__ offs,
                                               const int* __restrict__ csr,
                                               const float* __restrict__ HhP,
                                               const float* __restrict__ bc,
                                               const float* __restrict__ aLp,
                                               const float* __restrict__ aHp,
                                               float* __restrict__ out,
                                               int sp) {
    const int lane = threadIdx.x & 63;
    const int wv = threadIdx.x >> 6;
    const int c = blockIdx.x * 4 + wv;   // one wave per node
    const int o0 = offs[c];
    const int o1 = offs[c + 1];
    const float dc = dinv[c];
    float acc = XW[(size_t)c * 64 + lane] * dc;   // self-loop (× dc again below)
    for (int i = o0; i < o1; ++i) {
        int r = csr[i];
        acc += XW[(size_t)r * 64 + lane] * dinv[r];
    }
    float hl = acc * dc + bc[lane];
    size_t idx = (size_t)c * 64 + lane;
    float hh = 0.f;
    for (int s = 0; s < sp; ++s) hh += HhP[(size_t)s * (NN * 64) + idx];
    out[idx] = aLp[0] * hl + aHp[0] * hh;
}

// ---------------- host ----------------
extern "C" void kernel_launch(void* const* d_in, const int* in_sizes, int n_in,
                              void* d_out, int out_size, void* d_ws, size_t ws_size,
                              hipStream_t stream) {
    const float* x  = (const float*)d_in[0];
    const int*   ei = (const int*)d_in[1];
    const float* Ls = (const float*)d_in[2];
    const float* Wh = (const float*)d_in[3];
    const float* Wc = (const float*)d_in[4];
    const float* bc = (const float*)d_in[5];
    const float* aL = (const float*)d_in[6];
    const float* aH = (const float*)d_in[7];
    float* out = (float*)d_out;

    // split-K count chosen from ws_size (constant across calls -> graph-safe)
    const size_t HHP1 = (size_t)NN * 64 * 4;   // 3,145,728 per split
    const size_t TAIL = 3145728 + 1572864 + 49152 + 49664 + 49152 + 786432 + 49152;
    int spshift;
    if (ws_size >= 8 * HHP1 + TAIL)      spshift = 3;
    else if (ws_size >= 2 * HHP1 + TAIL) spshift = 1;
    else                                 spshift = 0;
    const int sp = 1 << spshift;
    const int kchunk = NN >> spshift;

    char* ws = (char*)d_ws;
    size_t off = 0;
    float* HhP  = (float*)(ws + off); off += (size_t)sp * HHP1;
    float* XW   = (float*)(ws + off); off += 3145728;
    u16*   Rt   = (u16*)  (ws + off); off += 1572864;
    int*   deg  = (int*)  (ws + off); off += 49152;
    int*   offs = (int*)  (ws + off); off += 49664;
    int*   cur  = (int*)  (ws + off); off += 49152;
    int*   csr  = (int*)  (ws + off); off += 786432;
    float* dinv = (float*)(ws + off);

    hipMemsetAsync(deg, 0, NN * sizeof(int), stream);
    k_deg  <<<EE / 256, 256, 0, stream>>>(ei, deg);
    k_scan <<<1, 1024, 0, stream>>>(deg, offs, cur, dinv);
    k_csr  <<<EE / 256, 256, 0, stream>>>(ei, cur, csr);
    k_xw   <<<(NN / 256) * 64, 256, 0, stream>>>(x, Wh, Wc, Rt, XW);
    k_gemm <<<(NN / 128) * sp, 256, 0, stream>>>(Ls, Rt, HhP, spshift, kchunk);
    k_final<<<NN / 4, 256, 0, stream>>>(XW, dinv, offs, csr, HhP, bc, aL, aH, out, sp);
}